// Round 1
// baseline (10330.408 us; speedup 1.0000x reference)
//
#include <hip/hip_runtime.h>

// ---------------------------------------------------------------------------
// TIRGRNN: 2-layer GRU-like RNN. B=128, T=128, H=1024, L=2.
//   xp = einsum('bti,goi->tbgo', cur, Wx) + bx      (bulk GEMM per layer)
//   per step: hp = h @ Wh^T + bh; r=sig(xp0+hp0); z=sig(xp1+hp1);
//             n=tanh(xp2 + r*hp2); h = (1-z)*n + z*h
// Outputs: last_layer_hiddens [B,T,H] fp32, last_step_hiddens [L,B,H] fp32.
//
// Strategy: bf16 MFMA for all GEMM work (threshold 8e-2 permits), persistent
// cooperative kernel for the recurrence with a distributed-flag grid barrier,
// fp32 register carry for the recurrent state (no compounding bf16 rounding).
// ---------------------------------------------------------------------------

typedef __attribute__((ext_vector_type(8))) short short8;   // 8 x bf16
typedef __attribute__((ext_vector_type(4))) float f32x4;

#define BSZ   128
#define TSZ   128
#define HSZ   1024
#define R3H   3072
#define BTH   16777216   // B*T*H
#define BH    131072     // B*H

__device__ __forceinline__ float bf2f(unsigned short u) {
    unsigned x = ((unsigned)u) << 16;
    float f; __builtin_memcpy(&f, &x, 4); return f;
}
__device__ __forceinline__ unsigned short f2b(float f) {
    unsigned x; __builtin_memcpy(&x, &f, 4);
    x += 0x7fffu + ((x >> 16) & 1u);      // RNE
    return (unsigned short)(x >> 16);
}

// ---------------------------------------------------------------------------
// fp32 -> bf16 bulk convert (n4 = element count / 4)
// ---------------------------------------------------------------------------
__global__ void cvt_bf16(const float* __restrict__ s, unsigned short* __restrict__ d, int n4) {
    int i = blockIdx.x * blockDim.x + threadIdx.x;
    int st = gridDim.x * blockDim.x;
    for (; i < n4; i += st) {
        float4 v = ((const float4*)s)[i];
        ushort4 o;
        o.x = f2b(v.x); o.y = f2b(v.y); o.z = f2b(v.z); o.w = f2b(v.w);
        ((ushort4*)d)[i] = o;
    }
}

// ---------------------------------------------------------------------------
// Bulk projection GEMM: xp[t][row][b] = sum_k In[(b*T+t)*H+k] * W[row*H+k] + bias[row]
// In bf16 [(b*128+t)*1024+k], W bf16 [3072][1024], xp bf16 [128][3072][128].
// Tiles: 128 cols (one t, all b) x 128 W-rows, BK=32. MFMA 16x16x32 bf16.
// LDS chunk-major: slab per 16B k-chunk, padded (+16B) to dodge bank aliasing.
// ---------------------------------------------------------------------------
__global__ __launch_bounds__(256) void gemm_xp(
    const unsigned short* __restrict__ A,
    const unsigned short* __restrict__ W,
    const float* __restrict__ bias,
    unsigned short* __restrict__ xp)
{
    __shared__ unsigned short Wt[4 * 1032];   // 4 chunks x (128 rows * 8 + 8 pad) ushorts
    __shared__ unsigned short It[4 * 1032];

    const int tC  = blockIdx.x;        // time index == col tile
    const int n0  = blockIdx.y << 7;   // W-row base
    const int tid = threadIdx.x;
    const int lane = tid & 63, wv = tid >> 6;
    const int wrh = (wv >> 1) << 6;    // wave W-row half (0/64)
    const int clh = (wv & 1) << 6;     // wave col half (0/64)
    const int q = lane >> 4, mm = lane & 15;
    const int r0 = tid >> 2, c0 = tid & 3;

    f32x4 acc[4][4];
#pragma unroll
    for (int i = 0; i < 4; i++)
#pragma unroll
        for (int j = 0; j < 4; j++) acc[i][j] = (f32x4){0.f, 0.f, 0.f, 0.f};

    const unsigned short* wp0 = &W[(n0 + r0) * HSZ + c0 * 8];
    const unsigned short* wp1 = wp0 + 64 * HSZ;
    const unsigned short* ap0 = &A[(r0 * TSZ + tC) * HSZ + c0 * 8];
    const unsigned short* ap1 = &A[((r0 + 64) * TSZ + tC) * HSZ + c0 * 8];
    unsigned short* wdst0 = &Wt[c0 * 1032 + r0 * 8];
    unsigned short* wdst1 = &Wt[c0 * 1032 + (r0 + 64) * 8];
    unsigned short* idst0 = &It[c0 * 1032 + r0 * 8];
    unsigned short* idst1 = &It[c0 * 1032 + (r0 + 64) * 8];

    for (int kk = 0; kk < 32; kk++) {
        const int kb = kk << 5;
        uint4 w0 = *(const uint4*)(wp0 + kb);
        uint4 w1 = *(const uint4*)(wp1 + kb);
        uint4 a0 = *(const uint4*)(ap0 + kb);
        uint4 a1 = *(const uint4*)(ap1 + kb);
        __syncthreads();
        *(uint4*)wdst0 = w0; *(uint4*)wdst1 = w1;
        *(uint4*)idst0 = a0; *(uint4*)idst1 = a1;
        __syncthreads();
        short8 af[4], bf[4];
#pragma unroll
        for (int mi = 0; mi < 4; mi++)
            af[mi] = *(const short8*)&Wt[q * 1032 + (wrh + mi * 16 + mm) * 8];
#pragma unroll
        for (int ni = 0; ni < 4; ni++)
            bf[ni] = *(const short8*)&It[q * 1032 + (clh + ni * 16 + mm) * 8];
#pragma unroll
        for (int mi = 0; mi < 4; mi++)
#pragma unroll
            for (int ni = 0; ni < 4; ni++)
                acc[mi][ni] = __builtin_amdgcn_mfma_f32_16x16x32_bf16(af[mi], bf[ni], acc[mi][ni], 0, 0, 0);
    }

    unsigned short* slab = xp + tC * (R3H * BSZ);
#pragma unroll
    for (int mi = 0; mi < 4; mi++) {
#pragma unroll
        for (int r = 0; r < 4; r++) {
            const int wrow = n0 + wrh + mi * 16 + q * 4 + r;
            const float bs = bias[wrow];
#pragma unroll
            for (int ni = 0; ni < 4; ni++) {
                const int b = clh + ni * 16 + mm;
                slab[wrow * BSZ + b] = f2b(acc[mi][ni][r] + bs);
            }
        }
    }
}

// ---------------------------------------------------------------------------
// Distributed-flag grid barrier (256 workgroups). flags zeroed before launch.
// ---------------------------------------------------------------------------
__device__ __forceinline__ void gridbar(unsigned* flags, unsigned s) {
    __builtin_amdgcn_fence(__ATOMIC_RELEASE, "agent");
    __syncthreads();
    if (threadIdx.x == 0)
        __hip_atomic_store(&flags[blockIdx.x], s, __ATOMIC_RELAXED, __HIP_MEMORY_SCOPE_AGENT);
    if (threadIdx.x < 64) {
#pragma unroll
        for (int j = 0; j < 4; ++j) {
            const unsigned idx = threadIdx.x + (j << 6);
            while (__hip_atomic_load(&flags[idx], __ATOMIC_RELAXED, __HIP_MEMORY_SCOPE_AGENT) < s)
                __builtin_amdgcn_s_sleep(1);
        }
    }
    __builtin_amdgcn_fence(__ATOMIC_ACQUIRE, "agent");
    __syncthreads();
}

// ---------------------------------------------------------------------------
// Persistent recurrence kernel. 256 wgs (one/CU), 384 threads = 6 waves.
// wg (ob,bb): outputs o in [ob*16, ob*16+16), batch b in [bb*32, bb*32+32).
// Wave w: gate g=w/2, batch-half mh=w%2  ->  one 16x16 MFMA tile, K=1024.
// Wh rows for k<512 held in LDS for all steps; k>=512 streamed from L2.
// h ping-pong in global bf16 via agent-scope atomics; fp32 carry in registers.
// ---------------------------------------------------------------------------
__global__ __launch_bounds__(384) void rnn_layer(
    const unsigned short* __restrict__ Whb,   // layer slice [3072][1024] bf16
    const unsigned short* __restrict__ xp,    // [128][3072][128] bf16
    const float* __restrict__ h0,             // [128][1024] fp32
    const float* __restrict__ bh,             // [3][1024] fp32
    unsigned short* __restrict__ hb0,
    unsigned short* __restrict__ hb1,
    unsigned short* __restrict__ seqout,      // layer0: bf16 [(b*128+t)*1024+o]
    float* __restrict__ lastlayer,            // layer1: fp32 [(b*128+t)*1024+o]
    float* __restrict__ laststep,             // fp32 [b*1024+o]
    unsigned* __restrict__ flags,
    int is_last)
{
    __shared__ unsigned short WhL[64 * 48 * 8];   // 48 KB: chunk-major [c<64][row<48] x 16B
    __shared__ float Cg[3][32][16];               // 6 KB gate staging

    const int bid = blockIdx.x;
    const int ob = bid >> 2, bb = bid & 3;
    const int tid = threadIdx.x;
    const int lane = tid & 63, wv = tid >> 6;

    // stage Wh (k < 512) into LDS
    for (int s = tid; s < 3072; s += 384) {
        const int c = s / 48, r = s - c * 48;
        const int g = r >> 4, o = r & 15;
        uint4 v = *(const uint4*)&Whb[((g << 10) + (ob << 4) + o) * HSZ + (c << 3)];
        *(uint4*)&WhL[(c * 48 + r) << 3] = v;
    }

    // per-thread elementwise ownership + fp32 carry registers
    float hc0 = 0.f, hc1 = 0.f;
    float eb00 = 0.f, eb01 = 0.f, eb10 = 0.f, eb11 = 0.f, eb20 = 0.f, eb21 = 0.f;
    int b_g_e = 0, o_g_e = 0;
    if (tid < 256) {
        const int b_l = tid >> 3, o2 = (tid & 7) << 1;
        b_g_e = (bb << 5) + b_l;
        o_g_e = (ob << 4) + o2;
        float2 v = *(const float2*)&h0[(b_g_e << 10) + o_g_e];
        hc0 = v.x; hc1 = v.y;
        eb00 = bh[o_g_e];        eb01 = bh[o_g_e + 1];
        eb10 = bh[1024 + o_g_e]; eb11 = bh[1024 + o_g_e + 1];
        eb20 = bh[2048 + o_g_e]; eb21 = bh[2048 + o_g_e + 1];
        unsigned pk = (unsigned)f2b(v.x) | ((unsigned)f2b(v.y) << 16);
        __hip_atomic_store((unsigned*)&hb0[(b_g_e << 10) + o_g_e], pk,
                           __ATOMIC_RELAXED, __HIP_MEMORY_SCOPE_AGENT);
    }
    gridbar(flags, 1u);

    const int g  = wv >> 1, mh = wv & 1;
    const int q  = lane >> 4, mm = lane & 15;
    const int b_row = (bb << 5) + (mh << 4) + mm;                      // A row (batch)
    const int wr = (g << 4) + mm;                                      // LDS slice row
    const unsigned short* bgp = &Whb[((g << 10) + (ob << 4) + mm) * HSZ + (q << 3)];

    unsigned sbar = 2;
    for (int t = 0; t < TSZ; t++) {
        const unsigned short* hr = (t & 1) ? hb1 : hb0;
        unsigned short* hw = (t & 1) ? hb0 : hb1;

        f32x4 acc0 = (f32x4){0.f, 0.f, 0.f, 0.f};
        f32x4 acc1 = (f32x4){0.f, 0.f, 0.f, 0.f};
        const unsigned short* ap = &hr[(b_row << 10) + (q << 3)];
#pragma unroll
        for (int s = 0; s < 16; s += 2) {        // k < 512 : Wh from LDS
            short8 a0 = *(const short8*)(ap + (s << 5));
            short8 b0 = *(const short8*)&WhL[((s * 4 + q) * 48 + wr) << 3];
            acc0 = __builtin_amdgcn_mfma_f32_16x16x32_bf16(a0, b0, acc0, 0, 0, 0);
            short8 a1 = *(const short8*)(ap + ((s + 1) << 5));
            short8 b1 = *(const short8*)&WhL[(((s + 1) * 4 + q) * 48 + wr) << 3];
            acc1 = __builtin_amdgcn_mfma_f32_16x16x32_bf16(a1, b1, acc1, 0, 0, 0);
        }
#pragma unroll
        for (int s = 16; s < 32; s += 2) {       // k >= 512 : Wh from L2
            short8 a0 = *(const short8*)(ap + (s << 5));
            short8 b0 = *(const short8*)(bgp + (s << 5));
            acc0 = __builtin_amdgcn_mfma_f32_16x16x32_bf16(a0, b0, acc0, 0, 0, 0);
            short8 a1 = *(const short8*)(ap + ((s + 1) << 5));
            short8 b1 = *(const short8*)(bgp + ((s + 1) << 5));
            acc1 = __builtin_amdgcn_mfma_f32_16x16x32_bf16(a1, b1, acc1, 0, 0, 0);
        }
        f32x4 accs = acc0 + acc1;
        {
            const int bl = (mh << 4) + (q << 2);
            Cg[g][bl + 0][mm] = accs[0];
            Cg[g][bl + 1][mm] = accs[1];
            Cg[g][bl + 2][mm] = accs[2];
            Cg[g][bl + 3][mm] = accs[3];
        }
        __syncthreads();

        if (tid < 256) {
            const unsigned short* xpt = xp + t * (R3H * BSZ);
            const int b_l = tid >> 3, o2 = (tid & 7) << 1;
            float res0, res1;
            {
                const float c0 = Cg[0][b_l][o2] + eb00;
                const float c1 = Cg[1][b_l][o2] + eb10;
                const float c2 = Cg[2][b_l][o2] + eb20;
                const float x0 = bf2f(xpt[o_g_e * BSZ + b_g_e]);
                const float x1 = bf2f(xpt[(1024 + o_g_e) * BSZ + b_g_e]);
                const float x2 = bf2f(xpt[(2048 + o_g_e) * BSZ + b_g_e]);
                const float r_ = 1.f / (1.f + __expf(-(x0 + c0)));
                const float z_ = 1.f / (1.f + __expf(-(x1 + c1)));
                const float nn = x2 + r_ * c2;
                const float th = 1.f - 2.f / (__expf(2.f * nn) + 1.f);
                res0 = (1.f - z_) * th + z_ * hc0;
            }
            {
                const int og1 = o_g_e + 1;
                const float c0 = Cg[0][b_l][o2 + 1] + eb01;
                const float c1 = Cg[1][b_l][o2 + 1] + eb11;
                const float c2 = Cg[2][b_l][o2 + 1] + eb21;
                const float x0 = bf2f(xpt[og1 * BSZ + b_g_e]);
                const float x1 = bf2f(xpt[(1024 + og1) * BSZ + b_g_e]);
                const float x2 = bf2f(xpt[(2048 + og1) * BSZ + b_g_e]);
                const float r_ = 1.f / (1.f + __expf(-(x0 + c0)));
                const float z_ = 1.f / (1.f + __expf(-(x1 + c1)));
                const float nn = x2 + r_ * c2;
                const float th = 1.f - 2.f / (__expf(2.f * nn) + 1.f);
                res1 = (1.f - z_) * th + z_ * hc1;
            }
            hc0 = res0; hc1 = res1;
            const unsigned pk = (unsigned)f2b(res0) | ((unsigned)f2b(res1) << 16);
            __hip_atomic_store((unsigned*)&hw[(b_g_e << 10) + o_g_e], pk,
                               __ATOMIC_RELAXED, __HIP_MEMORY_SCOPE_AGENT);
            if (!is_last) {
                *(unsigned*)&seqout[(b_g_e * TSZ + t) * HSZ + o_g_e] = pk;
            } else {
                float2 fv; fv.x = res0; fv.y = res1;
                *(float2*)&lastlayer[(b_g_e * TSZ + t) * HSZ + o_g_e] = fv;
            }
            if (t == TSZ - 1) {
                float2 fv; fv.x = res0; fv.y = res1;
                *(float2*)&laststep[(b_g_e << 10) + o_g_e] = fv;
            }
        }
        gridbar(flags, sbar++);
    }
}

// ---------------------------------------------------------------------------
// Host orchestration. ws layout (bytes):
//   Wxb 0..12582912 | Whb ..25165824 | inb ..58720256 | h1seq ..92274688 |
//   xp ..192937984 | hb0 ..193200128 | hb1 ..193462272 | flags(2KB)
// Requires ws_size >= ~185 MiB.
// ---------------------------------------------------------------------------
extern "C" void kernel_launch(void* const* d_in, const int* in_sizes, int n_in,
                              void* d_out, int out_size, void* d_ws, size_t ws_size,
                              hipStream_t stream)
{
    const float* input = (const float*)d_in[0];   // [128][128][1024]
    const float* prevh = (const float*)d_in[1];   // [2][128][1024]
    const float* Wx    = (const float*)d_in[2];   // [2][3][1024][1024]
    const float* Wh    = (const float*)d_in[3];
    const float* bx    = (const float*)d_in[4];   // [2][3][1024]
    const float* bh    = (const float*)d_in[5];
    float* out = (float*)d_out;

    char* ws = (char*)d_ws;
    unsigned short* Wxb = (unsigned short*)(ws);
    unsigned short* Whb = (unsigned short*)(ws + 12582912);
    unsigned short* inb = (unsigned short*)(ws + 25165824);
    unsigned short* h1s = (unsigned short*)(ws + 58720256);
    unsigned short* xp  = (unsigned short*)(ws + 92274688);
    unsigned short* hb0 = (unsigned short*)(ws + 192937984);
    unsigned short* hb1 = (unsigned short*)(ws + 193200128);
    unsigned*       flg = (unsigned*)(ws + 193462272);

    (void)hipMemsetAsync(flg, 0, 2048, stream);

    cvt_bf16<<<2048, 256, 0, stream>>>(input, inb, BTH / 4);
    cvt_bf16<<<1024, 256, 0, stream>>>(Wx, Wxb, 6291456 / 4);
    cvt_bf16<<<1024, 256, 0, stream>>>(Wh, Whb, 6291456 / 4);

    // ---- layer 0 ----
    gemm_xp<<<dim3(128, 24), 256, 0, stream>>>(inb, Wxb, bx, xp);
    {
        const unsigned short* a0 = Whb;
        const unsigned short* a1 = xp;
        const float* a2 = prevh;
        const float* a3 = bh;
        unsigned short* a4 = hb0;
        unsigned short* a5 = hb1;
        unsigned short* a6 = h1s;
        float* a7 = out;                  // unused for layer 0
        float* a8 = out + BTH;            // last_step layer 0
        unsigned* a9 = flg;
        int a10 = 0;
        void* args[] = {&a0, &a1, &a2, &a3, &a4, &a5, &a6, &a7, &a8, &a9, &a10};
        (void)hipLaunchCooperativeKernel((const void*)rnn_layer, dim3(256), dim3(384),
                                         args, 0, stream);
    }
    // ---- layer 1 ----
    gemm_xp<<<dim3(128, 24), 256, 0, stream>>>(h1s, Wxb + 3145728, bx + R3H, xp);
    {
        const unsigned short* a0 = Whb + 3145728;
        const unsigned short* a1 = xp;
        const float* a2 = prevh + BH;
        const float* a3 = bh + R3H;
        unsigned short* a4 = hb0;
        unsigned short* a5 = hb1;
        unsigned short* a6 = h1s;         // unused for layer 1
        float* a7 = out;                  // last_layer_hiddens
        float* a8 = out + BTH + BH;       // last_step layer 1
        unsigned* a9 = flg + 256;
        int a10 = 1;
        void* args[] = {&a0, &a1, &a2, &a3, &a4, &a5, &a6, &a7, &a8, &a9, &a10};
        (void)hipLaunchCooperativeKernel((const void*)rnn_layer, dim3(256), dim3(384),
                                         args, 0, stream);
    }
}

// Round 2
// 5149.524 us; speedup vs baseline: 2.0061x; 2.0061x over previous
//
#include <hip/hip_runtime.h>

// ---------------------------------------------------------------------------
// TIRGRNN: 2-layer GRU-like RNN. B=128, T=128, H=1024, L=2.
// R2: fence-free grid barrier (all cross-wg data via L3 through sc0sc1
// bypass loads / agent atomic stores), 128-wg retile (32o x 32b), LDS h-stage.
// ---------------------------------------------------------------------------

typedef __attribute__((ext_vector_type(8))) short short8;   // 8 x bf16
typedef __attribute__((ext_vector_type(4))) float f32x4;
typedef __attribute__((ext_vector_type(4))) unsigned int u32x4;

#define BSZ   128
#define TSZ   128
#define HSZ   1024
#define R3H   3072
#define BTH   16777216   // B*T*H
#define BH    131072     // B*H
#define NWG   128

__device__ __forceinline__ float bf2f(unsigned short u) {
    unsigned x = ((unsigned)u) << 16;
    float f; __builtin_memcpy(&f, &x, 4); return f;
}
__device__ __forceinline__ unsigned short f2b(float f) {
    unsigned x; __builtin_memcpy(&x, &f, 4);
    x += 0x7fffu + ((x >> 16) & 1u);      // RNE
    return (unsigned short)(x >> 16);
}

// ---------------------------------------------------------------------------
// fp32 -> bf16 bulk convert (n4 = element count / 4)
// ---------------------------------------------------------------------------
__global__ void cvt_bf16(const float* __restrict__ s, unsigned short* __restrict__ d, int n4) {
    int i = blockIdx.x * blockDim.x + threadIdx.x;
    int st = gridDim.x * blockDim.x;
    for (; i < n4; i += st) {
        float4 v = ((const float4*)s)[i];
        ushort4 o;
        o.x = f2b(v.x); o.y = f2b(v.y); o.z = f2b(v.z); o.w = f2b(v.w);
        ((ushort4*)d)[i] = o;
    }
}

// ---------------------------------------------------------------------------
// Bulk projection GEMM (unchanged from R1, known-good):
// xp[t][row][b] = sum_k In[(b*T+t)*H+k] * W[row*H+k] + bias[row]
// ---------------------------------------------------------------------------
__global__ __launch_bounds__(256) void gemm_xp(
    const unsigned short* __restrict__ A,
    const unsigned short* __restrict__ W,
    const float* __restrict__ bias,
    unsigned short* __restrict__ xp)
{
    __shared__ unsigned short Wt[4 * 1032];
    __shared__ unsigned short It[4 * 1032];

    const int tC  = blockIdx.x;
    const int n0  = blockIdx.y << 7;
    const int tid = threadIdx.x;
    const int lane = tid & 63, wv = tid >> 6;
    const int wrh = (wv >> 1) << 6;
    const int clh = (wv & 1) << 6;
    const int q = lane >> 4, mm = lane & 15;
    const int r0 = tid >> 2, c0 = tid & 3;

    f32x4 acc[4][4];
#pragma unroll
    for (int i = 0; i < 4; i++)
#pragma unroll
        for (int j = 0; j < 4; j++) acc[i][j] = (f32x4){0.f, 0.f, 0.f, 0.f};

    const unsigned short* wp0 = &W[(n0 + r0) * HSZ + c0 * 8];
    const unsigned short* wp1 = wp0 + 64 * HSZ;
    const unsigned short* ap0 = &A[(r0 * TSZ + tC) * HSZ + c0 * 8];
    const unsigned short* ap1 = &A[((r0 + 64) * TSZ + tC) * HSZ + c0 * 8];
    unsigned short* wdst0 = &Wt[c0 * 1032 + r0 * 8];
    unsigned short* wdst1 = &Wt[c0 * 1032 + (r0 + 64) * 8];
    unsigned short* idst0 = &It[c0 * 1032 + r0 * 8];
    unsigned short* idst1 = &It[c0 * 1032 + (r0 + 64) * 8];

    for (int kk = 0; kk < 32; kk++) {
        const int kb = kk << 5;
        uint4 w0 = *(const uint4*)(wp0 + kb);
        uint4 w1 = *(const uint4*)(wp1 + kb);
        uint4 a0 = *(const uint4*)(ap0 + kb);
        uint4 a1 = *(const uint4*)(ap1 + kb);
        __syncthreads();
        *(uint4*)wdst0 = w0; *(uint4*)wdst1 = w1;
        *(uint4*)idst0 = a0; *(uint4*)idst1 = a1;
        __syncthreads();
        short8 af[4], bf[4];
#pragma unroll
        for (int mi = 0; mi < 4; mi++)
            af[mi] = *(const short8*)&Wt[q * 1032 + (wrh + mi * 16 + mm) * 8];
#pragma unroll
        for (int ni = 0; ni < 4; ni++)
            bf[ni] = *(const short8*)&It[q * 1032 + (clh + ni * 16 + mm) * 8];
#pragma unroll
        for (int mi = 0; mi < 4; mi++)
#pragma unroll
            for (int ni = 0; ni < 4; ni++)
                acc[mi][ni] = __builtin_amdgcn_mfma_f32_16x16x32_bf16(af[mi], bf[ni], acc[mi][ni], 0, 0, 0);
    }

    unsigned short* slab = xp + tC * (R3H * BSZ);
#pragma unroll
    for (int mi = 0; mi < 4; mi++) {
#pragma unroll
        for (int r = 0; r < 4; r++) {
            const int wrow = n0 + wrh + mi * 16 + q * 4 + r;
            const float bs = bias[wrow];
#pragma unroll
            for (int ni = 0; ni < 4; ni++) {
                const int b = clh + ni * 16 + mm;
                slab[wrow * BSZ + b] = f2b(acc[mi][ni][r] + bs);
            }
        }
    }
}

// ---------------------------------------------------------------------------
// Fence-free grid barrier: per-wave vmcnt drain orders the (L2-bypassing)
// h stores before the flag store; consumers re-read h with bypass loads, so
// no cache invalidation is needed. L2 stays warm with Wh/xp.
// ---------------------------------------------------------------------------
__device__ __forceinline__ void gridbar(unsigned* flags, unsigned s) {
    asm volatile("s_waitcnt vmcnt(0)" ::: "memory");
    __syncthreads();
    if (threadIdx.x == 0)
        __hip_atomic_store(&flags[blockIdx.x], s, __ATOMIC_RELAXED, __HIP_MEMORY_SCOPE_AGENT);
    if (threadIdx.x < 64) {
#pragma unroll
        for (int j = 0; j < NWG / 64; ++j) {
            const unsigned idx = threadIdx.x + (j << 6);
            while (__hip_atomic_load(&flags[idx], __ATOMIC_RELAXED, __HIP_MEMORY_SCOPE_AGENT) < s)
                __builtin_amdgcn_s_sleep(1);
        }
    }
    __syncthreads();
}

// ---------------------------------------------------------------------------
// Persistent recurrence kernel. 128 wgs x 384 thr (6 waves).
// wg (ob,bb): o in [ob*32,+32), b in [bb*32,+32).
// Per step: stage h slice (32 rows x 1024 k bf16, 64 KB) into LDS via sc0sc1
// bypass loads (one L3 round trip); 6 waves = 3 gates x 2 batch-halves, each
// computes two 16x16 o-subtiles (A-fragment shared); Wh streams from warm L2.
// Cg aliases the dead h-stage LDS. h ping-pong via agent atomics; fp32 carry.
// ---------------------------------------------------------------------------
__global__ __launch_bounds__(384) void rnn_layer(
    const unsigned short* __restrict__ Whb,   // layer slice [3072][1024] bf16
    const unsigned short* __restrict__ xp,    // [128][3072][128] bf16
    const float* __restrict__ h0,             // [128][1024] fp32
    const float* __restrict__ bh,             // [3][1024] fp32
    unsigned short* __restrict__ hb0,
    unsigned short* __restrict__ hb1,
    unsigned short* __restrict__ seqout,      // layer0 out: bf16 [(b*128+t)*1024+o]
    float* __restrict__ lastlayer,            // layer1 out: fp32
    float* __restrict__ laststep,             // fp32 [b*1024+o]
    unsigned* __restrict__ flags,
    int is_last)
{
    __shared__ union {
        unsigned short hs[128 * 32 * 8];      // 64 KB: chunk-major [c<128][r<32] x 16B
        float cg[3][32][32];                  // 12 KB, alias (hs dead when written)
    } u;

    const int bid = blockIdx.x;
    const int ob = bid >> 2, bb = bid & 3;    // 32 ob x 4 bb
    const int tid = threadIdx.x;
    const int lane = tid & 63, wv = tid >> 6;

    // ---- elementwise ownership: tid<256 owns (b_l, o4..o4+3) ----
    float hc[4] = {0.f, 0.f, 0.f, 0.f};
    float bh0[4], bh1[4], bh2[4];
    int b_g = 0, o_g = 0, b_l = 0, o4 = 0;
    if (tid < 256) {
        b_l = tid >> 3; o4 = (tid & 7) << 2;
        b_g = (bb << 5) + b_l;
        o_g = (ob << 5) + o4;
        float4 v = *(const float4*)&h0[(b_g << 10) + o_g];
        hc[0] = v.x; hc[1] = v.y; hc[2] = v.z; hc[3] = v.w;
        *(float4*)bh0 = *(const float4*)&bh[o_g];
        *(float4*)bh1 = *(const float4*)&bh[1024 + o_g];
        *(float4*)bh2 = *(const float4*)&bh[2048 + o_g];
        unsigned long long pk = (unsigned long long)f2b(v.x)
            | ((unsigned long long)f2b(v.y) << 16)
            | ((unsigned long long)f2b(v.z) << 32)
            | ((unsigned long long)f2b(v.w) << 48);
        __hip_atomic_store((unsigned long long*)&hb0[(b_g << 10) + o_g], pk,
                           __ATOMIC_RELAXED, __HIP_MEMORY_SCOPE_AGENT);
    }
    gridbar(flags, 1u);

    // ---- matrix-wave constants ----
    const int g  = wv >> 1, bh_ = wv & 1;     // gate, batch-half
    const int q  = lane >> 4, mm = lane & 15;
    const unsigned short* wp = &Whb[(((g << 10) + (ob << 5) + mm) << 10) + (q << 3)];
    const unsigned short* hsb = (const unsigned short*)u.hs + ((q << 5) + (bh_ << 4) + mm) * 8;

    // ---- h-stage constants (tid<256): row r, chunk base c0 ----
    const int sr = tid >> 3, sc0 = tid & 7;

    for (int t = 0; t < TSZ; t++) {
        const unsigned short* hr = (t & 1) ? hb1 : hb0;
        unsigned short* hw = (t & 1) ? hb0 : hb1;

        // preload xp for this step (normal cached loads, read-only data)
        unsigned short xr[12];
        if (tid < 256) {
            const unsigned short* xpt = xp + t * (R3H * BSZ);
#pragma unroll
            for (int gg = 0; gg < 3; gg++)
#pragma unroll
                for (int j = 0; j < 4; j++)
                    xr[gg * 4 + j] = xpt[(((gg << 10) + o_g + j) << 7) + b_g];
        }

        // ---- stage h slice into LDS via L2-bypass loads ----
        if (tid < 256) {
            const unsigned short* src = hr + (((bb << 5) + sr) << 10) + (sc0 << 3);
            u32x4 hv[16];
#pragma unroll
            for (int i = 0; i < 16; i++)
                asm volatile("global_load_dwordx4 %0, %1, off sc0 sc1"
                             : "=v"(hv[i]) : "v"(src + (i << 6)));
            asm volatile("s_waitcnt vmcnt(0)" ::: "memory");
#pragma unroll
            for (int i = 0; i < 16; i++)
                *(u32x4*)&u.hs[(((sc0 + (i << 3)) << 5) + sr) << 3] = hv[i];
        }
        __syncthreads();

        // ---- MFMA: hp = h @ Wh^T for (g, 2 o-subtiles, batch-half) ----
        f32x4 acc0 = (f32x4){0.f, 0.f, 0.f, 0.f};
        f32x4 acc1 = (f32x4){0.f, 0.f, 0.f, 0.f};
#pragma unroll
        for (int s = 0; s < 32; s++) {
            short8 a  = *(const short8*)(hsb + (s << 10));
            short8 b0 = *(const short8*)(wp + (s << 5));
            short8 b1 = *(const short8*)(wp + (1 << 14) + (s << 5));
            acc0 = __builtin_amdgcn_mfma_f32_16x16x32_bf16(a, b0, acc0, 0, 0, 0);
            acc1 = __builtin_amdgcn_mfma_f32_16x16x32_bf16(a, b1, acc1, 0, 0, 0);
        }
        __syncthreads();   // hs dead -> safe to write aliased cg

        {
            const int bl = (bh_ << 4) + (q << 2);
#pragma unroll
            for (int r = 0; r < 4; r++) {
                u.cg[g][bl + r][mm]      = acc0[r];
                u.cg[g][bl + r][16 + mm] = acc1[r];
            }
        }
        __syncthreads();

        // ---- elementwise gates + h update ----
        if (tid < 256) {
            float res[4];
#pragma unroll
            for (int j = 0; j < 4; j++) {
                const int oo = o4 + j;
                const float c0 = u.cg[0][b_l][oo] + bh0[j];
                const float c1 = u.cg[1][b_l][oo] + bh1[j];
                const float c2 = u.cg[2][b_l][oo] + bh2[j];
                const float x0 = bf2f(xr[j]);
                const float x1 = bf2f(xr[4 + j]);
                const float x2 = bf2f(xr[8 + j]);
                const float r_ = 1.f / (1.f + __expf(-(x0 + c0)));
                const float z_ = 1.f / (1.f + __expf(-(x1 + c1)));
                const float nn = x2 + r_ * c2;
                const float th = 1.f - 2.f / (__expf(2.f * nn) + 1.f);
                res[j] = (1.f - z_) * th + z_ * hc[j];
                hc[j] = res[j];
            }
            const unsigned long long pk = (unsigned long long)f2b(res[0])
                | ((unsigned long long)f2b(res[1]) << 16)
                | ((unsigned long long)f2b(res[2]) << 32)
                | ((unsigned long long)f2b(res[3]) << 48);
            __hip_atomic_store((unsigned long long*)&hw[(b_g << 10) + o_g], pk,
                               __ATOMIC_RELAXED, __HIP_MEMORY_SCOPE_AGENT);
            if (!is_last) {
                *(unsigned long long*)&seqout[(b_g * TSZ + t) * HSZ + o_g] = pk;
            } else {
                float4 fv; fv.x = res[0]; fv.y = res[1]; fv.z = res[2]; fv.w = res[3];
                *(float4*)&lastlayer[((b_g * TSZ + t) << 10) + o_g] = fv;
            }
            if (t == TSZ - 1) {
                float4 fv; fv.x = res[0]; fv.y = res[1]; fv.z = res[2]; fv.w = res[3];
                *(float4*)&laststep[(b_g << 10) + o_g] = fv;
            }
        }
        gridbar(flags, (unsigned)(t + 2));
    }
}

// ---------------------------------------------------------------------------
// Host orchestration. ws layout (bytes):
//   Wxb 0..12582912 | Whb ..25165824 | inb ..58720256 | h1seq ..92274688 |
//   xp ..192937984 | hb0 ..193200128 | hb1 ..193462272 | flags(2KB)
// ---------------------------------------------------------------------------
extern "C" void kernel_launch(void* const* d_in, const int* in_sizes, int n_in,
                              void* d_out, int out_size, void* d_ws, size_t ws_size,
                              hipStream_t stream)
{
    const float* input = (const float*)d_in[0];
    const float* prevh = (const float*)d_in[1];
    const float* Wx    = (const float*)d_in[2];
    const float* Wh    = (const float*)d_in[3];
    const float* bx    = (const float*)d_in[4];
    const float* bh    = (const float*)d_in[5];
    float* out = (float*)d_out;

    char* ws = (char*)d_ws;
    unsigned short* Wxb = (unsigned short*)(ws);
    unsigned short* Whb = (unsigned short*)(ws + 12582912);
    unsigned short* inb = (unsigned short*)(ws + 25165824);
    unsigned short* h1s = (unsigned short*)(ws + 58720256);
    unsigned short* xp  = (unsigned short*)(ws + 92274688);
    unsigned short* hb0 = (unsigned short*)(ws + 192937984);
    unsigned short* hb1 = (unsigned short*)(ws + 193200128);
    unsigned*       flg = (unsigned*)(ws + 193462272);

    (void)hipMemsetAsync(flg, 0, 2048, stream);

    cvt_bf16<<<2048, 256, 0, stream>>>(input, inb, BTH / 4);
    cvt_bf16<<<1024, 256, 0, stream>>>(Wx, Wxb, 6291456 / 4);
    cvt_bf16<<<1024, 256, 0, stream>>>(Wh, Whb, 6291456 / 4);

    // ---- layer 0 ----
    gemm_xp<<<dim3(128, 24), 256, 0, stream>>>(inb, Wxb, bx, xp);
    {
        const unsigned short* a0 = Whb;
        const unsigned short* a1 = xp;
        const float* a2 = prevh;
        const float* a3 = bh;
        unsigned short* a4 = hb0;
        unsigned short* a5 = hb1;
        unsigned short* a6 = h1s;
        float* a7 = out;
        float* a8 = out + BTH;            // last_step layer 0
        unsigned* a9 = flg;
        int a10 = 0;
        void* args[] = {&a0, &a1, &a2, &a3, &a4, &a5, &a6, &a7, &a8, &a9, &a10};
        (void)hipLaunchCooperativeKernel((const void*)rnn_layer, dim3(NWG), dim3(384),
                                         args, 0, stream);
    }
    // ---- layer 1 ----
    gemm_xp<<<dim3(128, 24), 256, 0, stream>>>(h1s, Wxb + 3145728, bx + R3H, xp);
    {
        const unsigned short* a0 = Whb + 3145728;
        const unsigned short* a1 = xp;
        const float* a2 = prevh + BH;
        const float* a3 = bh + R3H;
        unsigned short* a4 = hb0;
        unsigned short* a5 = hb1;
        unsigned short* a6 = h1s;
        float* a7 = out;                  // last_layer_hiddens
        float* a8 = out + BTH + BH;       // last_step layer 1
        unsigned* a9 = flg + 256;
        int a10 = 1;
        void* args[] = {&a0, &a1, &a2, &a3, &a4, &a5, &a6, &a7, &a8, &a9, &a10};
        (void)hipLaunchCooperativeKernel((const void*)rnn_layer, dim3(NWG), dim3(384),
                                         args, 0, stream);
    }
}

// Round 3
// 2685.256 us; speedup vs baseline: 3.8471x; 1.9177x over previous
//
#include <hip/hip_runtime.h>

// ---------------------------------------------------------------------------
// TIRGRNN: 2-layer GRU-like RNN. B=128, T=128, H=1024, L=2.
// R3: Wh held in registers (step-invariant), 256 wgs x 12 waves, m97-style
// conflict-free LDS h-slab, 4-way k-split with f32 partial reduction in LDS.
// Fence-free L3 grid barrier (R2-proven).
// ---------------------------------------------------------------------------

typedef __attribute__((ext_vector_type(8))) short short8;   // 8 x bf16
typedef __attribute__((ext_vector_type(4))) float f32x4;
typedef __attribute__((ext_vector_type(4))) unsigned int u32x4;

#define BSZ   128
#define TSZ   128
#define HSZ   1024
#define R3H   3072
#define BTH   16777216   // B*T*H
#define BH    131072     // B*H
#define NWG   256

__device__ __forceinline__ float bf2f(unsigned short u) {
    unsigned x = ((unsigned)u) << 16;
    float f; __builtin_memcpy(&f, &x, 4); return f;
}
__device__ __forceinline__ unsigned short f2b(float f) {
    unsigned x; __builtin_memcpy(&x, &f, 4);
    x += 0x7fffu + ((x >> 16) & 1u);      // RNE
    return (unsigned short)(x >> 16);
}

// ---------------------------------------------------------------------------
// fp32 -> bf16 bulk convert
// ---------------------------------------------------------------------------
__global__ void cvt_bf16(const float* __restrict__ s, unsigned short* __restrict__ d, int n4) {
    int i = blockIdx.x * blockDim.x + threadIdx.x;
    int st = gridDim.x * blockDim.x;
    for (; i < n4; i += st) {
        float4 v = ((const float4*)s)[i];
        ushort4 o;
        o.x = f2b(v.x); o.y = f2b(v.y); o.z = f2b(v.z); o.w = f2b(v.w);
        ((ushort4*)d)[i] = o;
    }
}

// ---------------------------------------------------------------------------
// Bulk projection GEMM (unchanged, known-good):
// xp[t][row][b] = sum_k In[(b*T+t)*H+k] * W[row*H+k] + bias[row]
// ---------------------------------------------------------------------------
__global__ __launch_bounds__(256) void gemm_xp(
    const unsigned short* __restrict__ A,
    const unsigned short* __restrict__ W,
    const float* __restrict__ bias,
    unsigned short* __restrict__ xp)
{
    __shared__ unsigned short Wt[4 * 1032];
    __shared__ unsigned short It[4 * 1032];

    const int tC  = blockIdx.x;
    const int n0  = blockIdx.y << 7;
    const int tid = threadIdx.x;
    const int lane = tid & 63, wv = tid >> 6;
    const int wrh = (wv >> 1) << 6;
    const int clh = (wv & 1) << 6;
    const int q = lane >> 4, mm = lane & 15;
    const int r0 = tid >> 2, c0 = tid & 3;

    f32x4 acc[4][4];
#pragma unroll
    for (int i = 0; i < 4; i++)
#pragma unroll
        for (int j = 0; j < 4; j++) acc[i][j] = (f32x4){0.f, 0.f, 0.f, 0.f};

    const unsigned short* wp0 = &W[(n0 + r0) * HSZ + c0 * 8];
    const unsigned short* wp1 = wp0 + 64 * HSZ;
    const unsigned short* ap0 = &A[(r0 * TSZ + tC) * HSZ + c0 * 8];
    const unsigned short* ap1 = &A[((r0 + 64) * TSZ + tC) * HSZ + c0 * 8];
    unsigned short* wdst0 = &Wt[c0 * 1032 + r0 * 8];
    unsigned short* wdst1 = &Wt[c0 * 1032 + (r0 + 64) * 8];
    unsigned short* idst0 = &It[c0 * 1032 + r0 * 8];
    unsigned short* idst1 = &It[c0 * 1032 + (r0 + 64) * 8];

    for (int kk = 0; kk < 32; kk++) {
        const int kb = kk << 5;
        uint4 w0 = *(const uint4*)(wp0 + kb);
        uint4 w1 = *(const uint4*)(wp1 + kb);
        uint4 a0 = *(const uint4*)(ap0 + kb);
        uint4 a1 = *(const uint4*)(ap1 + kb);
        __syncthreads();
        *(uint4*)wdst0 = w0; *(uint4*)wdst1 = w1;
        *(uint4*)idst0 = a0; *(uint4*)idst1 = a1;
        __syncthreads();
        short8 af[4], bf[4];
#pragma unroll
        for (int mi = 0; mi < 4; mi++)
            af[mi] = *(const short8*)&Wt[q * 1032 + (wrh + mi * 16 + mm) * 8];
#pragma unroll
        for (int ni = 0; ni < 4; ni++)
            bf[ni] = *(const short8*)&It[q * 1032 + (clh + ni * 16 + mm) * 8];
#pragma unroll
        for (int mi = 0; mi < 4; mi++)
#pragma unroll
            for (int ni = 0; ni < 4; ni++)
                acc[mi][ni] = __builtin_amdgcn_mfma_f32_16x16x32_bf16(af[mi], bf[ni], acc[mi][ni], 0, 0, 0);
    }

    unsigned short* slab = xp + tC * (R3H * BSZ);
#pragma unroll
    for (int mi = 0; mi < 4; mi++) {
#pragma unroll
        for (int r = 0; r < 4; r++) {
            const int wrow = n0 + wrh + mi * 16 + q * 4 + r;
            const float bs = bias[wrow];
#pragma unroll
            for (int ni = 0; ni < 4; ni++) {
                const int b = clh + ni * 16 + mm;
                slab[wrow * BSZ + b] = f2b(acc[mi][ni][r] + bs);
            }
        }
    }
}

// ---------------------------------------------------------------------------
// Fence-free grid barrier (R2-proven): vmcnt drain orders L2-bypassing data
// stores before the flag store; no cache maintenance, L2 stays warm.
// ---------------------------------------------------------------------------
__device__ __forceinline__ void gridbar(unsigned* flags, unsigned s) {
    asm volatile("s_waitcnt vmcnt(0)" ::: "memory");
    __syncthreads();
    if (threadIdx.x == 0)
        __hip_atomic_store(&flags[blockIdx.x], s, __ATOMIC_RELAXED, __HIP_MEMORY_SCOPE_AGENT);
    if (threadIdx.x < 64) {
#pragma unroll
        for (int j = 0; j < NWG / 64; ++j) {
            const unsigned idx = threadIdx.x + (j << 6);
            while (__hip_atomic_load(&flags[idx], __ATOMIC_RELAXED, __HIP_MEMORY_SCOPE_AGENT) < s)
                __builtin_amdgcn_s_sleep(1);
        }
    }
    __syncthreads();
}

// ---------------------------------------------------------------------------
// Persistent recurrence kernel. 256 wgs x 768 thr (12 waves, 3/SIMD).
// wg (bt,ot): b in [bt*16,+16), o in [ot*32,+32), all 3 gates.
// Wave wv=(g,kh)=(wv>>2, wv&3): holds Wh[g][o-sub 0/1][k-quarter kh] in
// 64 VGPRs for the whole sequence. Per step: stage h slab (16b x 1024k,
// 32 KB) into LDS via L3-bypass loads; 8x(ds_read_b128 + 2 MFMA); f32
// partials to padded Cg; elementwise combines 4 k-partials x 3 gates.
// LDS h-slab: chunk-major, 272 B slab stride (m97 mod-32 bank structure).
// ---------------------------------------------------------------------------
__global__ __launch_bounds__(768, 3) void rnn_layer(
    const unsigned short* __restrict__ Whb,   // layer slice [3072][1024] bf16
    const unsigned short* __restrict__ xp,    // [128][3072][128] bf16
    const float* __restrict__ h0,             // [128][1024] fp32
    const float* __restrict__ bh,             // [3][1024] fp32
    unsigned short* __restrict__ hb0,
    unsigned short* __restrict__ hb1,
    unsigned short* __restrict__ seqout,      // layer0 out: bf16 [(b*128+t)*1024+o]
    float* __restrict__ lastlayer,            // layer1 out: fp32
    float* __restrict__ laststep,             // fp32 [b*1024+o]
    unsigned* __restrict__ flags,
    int is_last)
{
    __shared__ unsigned short As[128 * 136];  // 34816 B: [kc<128] x (16b x 16B + 16B pad)
    __shared__ float Cg[6528];                // 26112 B: [3g][2os][4kh][16b][17]

    const int bid = blockIdx.x;
    const int bt = bid & 7, ot = bid >> 3;
    const int tid = threadIdx.x;
    const int lane = tid & 63, wv = tid >> 6;
    const int g = wv >> 2, kh = wv & 3;
    const int q = lane >> 4, mm = lane & 15;

    // ---- Wh fragments into registers (once) ----
    short8 wh0[8], wh1[8];
    {
        const unsigned short* p0 = &Whb[((g << 10) + (ot << 5) + mm) * HSZ + (kh << 8) + (q << 3)];
        const unsigned short* p1 = p0 + (HSZ << 4);   // +16 o-rows
#pragma unroll
        for (int s = 0; s < 8; s++) {
            wh0[s] = *(const short8*)(p0 + (s << 5));
            wh1[s] = *(const short8*)(p1 + (s << 5));
        }
    }

    // ---- elementwise ownership: tid<256 owns (b_l, o_l, o_l+1) ----
    float hc0 = 0.f, hc1 = 0.f;
    float bh00 = 0.f, bh01 = 0.f, bh10 = 0.f, bh11 = 0.f, bh20 = 0.f, bh21 = 0.f;
    int b_g = 0, o_g = 0, b_l = 0, o_l = 0;
    if (tid < 256) {
        b_l = tid >> 4; o_l = (tid & 15) << 1;
        b_g = (bt << 4) + b_l;
        o_g = (ot << 5) + o_l;
        float2 v = *(const float2*)&h0[(b_g << 10) + o_g];
        hc0 = v.x; hc1 = v.y;
        bh00 = bh[o_g];        bh01 = bh[o_g + 1];
        bh10 = bh[1024 + o_g]; bh11 = bh[1024 + o_g + 1];
        bh20 = bh[2048 + o_g]; bh21 = bh[2048 + o_g + 1];
        unsigned pk = (unsigned)f2b(v.x) | ((unsigned)f2b(v.y) << 16);
        __hip_atomic_store((unsigned*)&hb0[(b_g << 10) + o_g], pk,
                           __ATOMIC_RELAXED, __HIP_MEMORY_SCOPE_AGENT);
    }
    gridbar(flags, 1u);

    // staging constants (tid<512): b = sb, chunk group kcg
    const int sb = tid & 15, kcg = (tid >> 4) & 31;

    for (int t = 0; t < TSZ; t++) {
        const unsigned short* hr = (t & 1) ? hb1 : hb0;
        unsigned short* hw = (t & 1) ? hb0 : hb1;

        // xp preload for this step (cached loads; used after MFMA)
        unsigned short xr[6];
        if (tid < 256) {
            const unsigned short* xpt = xp + t * (R3H * BSZ);
#pragma unroll
            for (int gg = 0; gg < 3; gg++) {
                xr[gg * 2]     = xpt[(((gg << 10) + o_g) << 7) + b_g];
                xr[gg * 2 + 1] = xpt[(((gg << 10) + o_g + 1) << 7) + b_g];
            }
        }

        // ---- stage h slab via L3-bypass loads ----
        if (tid < 512) {
            const unsigned short* src = hr + (((bt << 4) + sb) << 10) + (kcg << 3);
            u32x4 hv[4];
#pragma unroll
            for (int i = 0; i < 4; i++)
                asm volatile("global_load_dwordx4 %0, %1, off sc0 sc1"
                             : "=v"(hv[i]) : "v"(src + (i << 8)));
            asm volatile("s_waitcnt vmcnt(0)" ::: "memory");
#pragma unroll
            for (int i = 0; i < 4; i++)
                *(u32x4*)&As[(kcg + (i << 5)) * 136 + sb * 8] = hv[i];
        }
        __syncthreads();

        // ---- k-loop: pure LDS + MFMA (Wh in registers) ----
        f32x4 acc0 = (f32x4){0.f, 0.f, 0.f, 0.f};
        f32x4 acc1 = (f32x4){0.f, 0.f, 0.f, 0.f};
        {
            const unsigned short* ab = &As[((kh << 5) + q) * 136 + mm * 8];
#pragma unroll
            for (int s = 0; s < 8; s++) {
                short8 a = *(const short8*)(ab + s * 544);   // +4 chunks
                acc0 = __builtin_amdgcn_mfma_f32_16x16x32_bf16(a, wh0[s], acc0, 0, 0, 0);
                acc1 = __builtin_amdgcn_mfma_f32_16x16x32_bf16(a, wh1[s], acc1, 0, 0, 0);
            }
        }

        // ---- write f32 partials: Cg[g][os][kh][b=q*4+r][o=mm], b-stride 17 ----
        {
            float* cgw = &Cg[((g << 3) + kh) * 272 + (q << 2) * 17 + mm];
#pragma unroll
            for (int r = 0; r < 4; r++) {
                cgw[r * 17]        = acc0[r];
                cgw[1088 + r * 17] = acc1[r];
            }
        }
        __syncthreads();

        // ---- elementwise: combine partials, gates, h update ----
        if (tid < 256) {
            const int os = o_l >> 4, ol2 = o_l & 15;
            const float* cb = &Cg[os * 1088 + b_l * 17 + ol2];
            float c0a, c0b, c1a, c1b, c2a, c2b;
            {
                float s0, s1;
                const float* p = cb;
                s0 = p[0] + p[272] + p[544] + p[816];
                s1 = p[1] + p[273] + p[545] + p[817];
                c0a = s0; c0b = s1;
                p = cb + 2176;
                s0 = p[0] + p[272] + p[544] + p[816];
                s1 = p[1] + p[273] + p[545] + p[817];
                c1a = s0; c1b = s1;
                p = cb + 4352;
                s0 = p[0] + p[272] + p[544] + p[816];
                s1 = p[1] + p[273] + p[545] + p[817];
                c2a = s0; c2b = s1;
            }
            float res0, res1;
            {
                const float x0 = bf2f(xr[0]), x1 = bf2f(xr[2]), x2 = bf2f(xr[4]);
                const float r_ = 1.f / (1.f + __expf(-(x0 + c0a + bh00)));
                const float z_ = 1.f / (1.f + __expf(-(x1 + c1a + bh10)));
                const float nn = x2 + r_ * (c2a + bh20);
                const float th = 1.f - 2.f / (__expf(2.f * nn) + 1.f);
                res0 = (1.f - z_) * th + z_ * hc0;
            }
            {
                const float x0 = bf2f(xr[1]), x1 = bf2f(xr[3]), x2 = bf2f(xr[5]);
                const float r_ = 1.f / (1.f + __expf(-(x0 + c0b + bh01)));
                const float z_ = 1.f / (1.f + __expf(-(x1 + c1b + bh11)));
                const float nn = x2 + r_ * (c2b + bh21);
                const float th = 1.f - 2.f / (__expf(2.f * nn) + 1.f);
                res1 = (1.f - z_) * th + z_ * hc1;
            }
            hc0 = res0; hc1 = res1;
            const unsigned pk = (unsigned)f2b(res0) | ((unsigned)f2b(res1) << 16);
            __hip_atomic_store((unsigned*)&hw[(b_g << 10) + o_g], pk,
                               __ATOMIC_RELAXED, __HIP_MEMORY_SCOPE_AGENT);
            if (!is_last) {
                *(unsigned*)&seqout[(b_g * TSZ + t) * HSZ + o_g] = pk;
            } else {
                float2 fv; fv.x = res0; fv.y = res1;
                *(float2*)&lastlayer[((b_g * TSZ + t) << 10) + o_g] = fv;
            }
            if (t == TSZ - 1) {
                float2 fv; fv.x = res0; fv.y = res1;
                *(float2*)&laststep[(b_g << 10) + o_g] = fv;
            }
        }
        gridbar(flags, (unsigned)(t + 2));
    }
}

// ---------------------------------------------------------------------------
// Host orchestration. ws layout (bytes):
//   Wxb 0..12582912 | Whb ..25165824 | inb ..58720256 | h1seq ..92274688 |
//   xp ..192937984 | hb0 ..193200128 | hb1 ..193462272 | flags(2KB)
// ---------------------------------------------------------------------------
extern "C" void kernel_launch(void* const* d_in, const int* in_sizes, int n_in,
                              void* d_out, int out_size, void* d_ws, size_t ws_size,
                              hipStream_t stream)
{
    const float* input = (const float*)d_in[0];
    const float* prevh = (const float*)d_in[1];
    const float* Wx    = (const float*)d_in[2];
    const float* Wh    = (const float*)d_in[3];
    const float* bx    = (const float*)d_in[4];
    const float* bh    = (const float*)d_in[5];
    float* out = (float*)d_out;

    char* ws = (char*)d_ws;
    unsigned short* Wxb = (unsigned short*)(ws);
    unsigned short* Whb = (unsigned short*)(ws + 12582912);
    unsigned short* inb = (unsigned short*)(ws + 25165824);
    unsigned short* h1s = (unsigned short*)(ws + 58720256);
    unsigned short* xp  = (unsigned short*)(ws + 92274688);
    unsigned short* hb0 = (unsigned short*)(ws + 192937984);
    unsigned short* hb1 = (unsigned short*)(ws + 193200128);
    unsigned*       flg = (unsigned*)(ws + 193462272);

    (void)hipMemsetAsync(flg, 0, 2048, stream);

    cvt_bf16<<<2048, 256, 0, stream>>>(input, inb, BTH / 4);
    cvt_bf16<<<1024, 256, 0, stream>>>(Wx, Wxb, 6291456 / 4);
    cvt_bf16<<<1024, 256, 0, stream>>>(Wh, Whb, 6291456 / 4);

    // ---- layer 0 ----
    gemm_xp<<<dim3(128, 24), 256, 0, stream>>>(inb, Wxb, bx, xp);
    {
        const unsigned short* a0 = Whb;
        const unsigned short* a1 = xp;
        const float* a2 = prevh;
        const float* a3 = bh;
        unsigned short* a4 = hb0;
        unsigned short* a5 = hb1;
        unsigned short* a6 = h1s;
        float* a7 = out;
        float* a8 = out + BTH;            // last_step layer 0
        unsigned* a9 = flg;
        int a10 = 0;
        void* args[] = {&a0, &a1, &a2, &a3, &a4, &a5, &a6, &a7, &a8, &a9, &a10};
        (void)hipLaunchCooperativeKernel((const void*)rnn_layer, dim3(NWG), dim3(768),
                                         args, 0, stream);
    }
    // ---- layer 1 ----
    gemm_xp<<<dim3(128, 24), 256, 0, stream>>>(h1s, Wxb + 3145728, bx + R3H, xp);
    {
        const unsigned short* a0 = Whb + 3145728;
        const unsigned short* a1 = xp;
        const float* a2 = prevh + BH;
        const float* a3 = bh + R3H;
        unsigned short* a4 = hb0;
        unsigned short* a5 = hb1;
        unsigned short* a6 = h1s;
        float* a7 = out;                  // last_layer_hiddens
        float* a8 = out + BTH + BH;       // last_step layer 1
        unsigned* a9 = flg + 256;
        int a10 = 1;
        void* args[] = {&a0, &a1, &a2, &a3, &a4, &a5, &a6, &a7, &a8, &a9, &a10};
        (void)hipLaunchCooperativeKernel((const void*)rnn_layer, dim3(NWG), dim3(768),
                                         args, 0, stream);
    }
}

// Round 4
// 2281.014 us; speedup vs baseline: 4.5289x; 1.1772x over previous
//
#include <hip/hip_runtime.h>

// ---------------------------------------------------------------------------
// TIRGRNN: 2-layer GRU-like RNN. B=128, T=128, H=1024, L=2.
// R4: one-pass barrier poll; xp transposed to [t][b][3H] (coalesced reads,
// no cross-XCD half-line waste); xp prefetched one step ahead (HBM latency
// off the serial chain). Wh-in-registers recurrence otherwise as R3.
// ---------------------------------------------------------------------------

typedef __attribute__((ext_vector_type(8))) short short8;   // 8 x bf16
typedef __attribute__((ext_vector_type(4))) float f32x4;
typedef __attribute__((ext_vector_type(4))) unsigned int u32x4;

#define BSZ   128
#define TSZ   128
#define HSZ   1024
#define R3H   3072
#define BTH   16777216   // B*T*H
#define BH    131072     // B*H
#define NWG   256

__device__ __forceinline__ float bf2f(unsigned short u) {
    unsigned x = ((unsigned)u) << 16;
    float f; __builtin_memcpy(&f, &x, 4); return f;
}
__device__ __forceinline__ unsigned short f2b(float f) {
    unsigned x; __builtin_memcpy(&x, &f, 4);
    x += 0x7fffu + ((x >> 16) & 1u);      // RNE
    return (unsigned short)(x >> 16);
}

// ---------------------------------------------------------------------------
// fp32 -> bf16 bulk convert
// ---------------------------------------------------------------------------
__global__ void cvt_bf16(const float* __restrict__ s, unsigned short* __restrict__ d, int n4) {
    int i = blockIdx.x * blockDim.x + threadIdx.x;
    int st = gridDim.x * blockDim.x;
    for (; i < n4; i += st) {
        float4 v = ((const float4*)s)[i];
        ushort4 o;
        o.x = f2b(v.x); o.y = f2b(v.y); o.z = f2b(v.z); o.w = f2b(v.w);
        ((ushort4*)d)[i] = o;
    }
}

// ---------------------------------------------------------------------------
// Bulk projection GEMM, transposed output:
// xp[t][b][row] = sum_k In[(b*T+t)*H+k] * W[row*H+k] + bias[row]
// (operands swapped vs R3: A-frag = input rows (m=b), B-frag = W rows (n).)
// ---------------------------------------------------------------------------
__global__ __launch_bounds__(256) void gemm_xp(
    const unsigned short* __restrict__ A,
    const unsigned short* __restrict__ W,
    const float* __restrict__ bias,
    unsigned short* __restrict__ xp)
{
    __shared__ unsigned short Wt[4 * 1032];
    __shared__ unsigned short It[4 * 1032];

    const int tC  = blockIdx.x;
    const int n0  = blockIdx.y << 7;
    const int tid = threadIdx.x;
    const int lane = tid & 63, wv = tid >> 6;
    const int mh = (wv >> 1) << 6;     // b half
    const int nh = (wv & 1) << 6;      // wrow half
    const int q = lane >> 4, mm = lane & 15;
    const int r0 = tid >> 2, c0 = tid & 3;

    f32x4 acc[4][4];
#pragma unroll
    for (int i = 0; i < 4; i++)
#pragma unroll
        for (int j = 0; j < 4; j++) acc[i][j] = (f32x4){0.f, 0.f, 0.f, 0.f};

    const unsigned short* wp0 = &W[(n0 + r0) * HSZ + c0 * 8];
    const unsigned short* wp1 = wp0 + 64 * HSZ;
    const unsigned short* ap0 = &A[(r0 * TSZ + tC) * HSZ + c0 * 8];
    const unsigned short* ap1 = &A[((r0 + 64) * TSZ + tC) * HSZ + c0 * 8];
    unsigned short* wdst0 = &Wt[c0 * 1032 + r0 * 8];
    unsigned short* wdst1 = &Wt[c0 * 1032 + (r0 + 64) * 8];
    unsigned short* idst0 = &It[c0 * 1032 + r0 * 8];
    unsigned short* idst1 = &It[c0 * 1032 + (r0 + 64) * 8];

    for (int kk = 0; kk < 32; kk++) {
        const int kb = kk << 5;
        uint4 w0 = *(const uint4*)(wp0 + kb);
        uint4 w1 = *(const uint4*)(wp1 + kb);
        uint4 a0 = *(const uint4*)(ap0 + kb);
        uint4 a1 = *(const uint4*)(ap1 + kb);
        __syncthreads();
        *(uint4*)wdst0 = w0; *(uint4*)wdst1 = w1;
        *(uint4*)idst0 = a0; *(uint4*)idst1 = a1;
        __syncthreads();
        short8 af[4], bf[4];
#pragma unroll
        for (int mi = 0; mi < 4; mi++)
            af[mi] = *(const short8*)&It[q * 1032 + (mh + mi * 16 + mm) * 8];
#pragma unroll
        for (int ni = 0; ni < 4; ni++)
            bf[ni] = *(const short8*)&Wt[q * 1032 + (nh + ni * 16 + mm) * 8];
#pragma unroll
        for (int mi = 0; mi < 4; mi++)
#pragma unroll
            for (int ni = 0; ni < 4; ni++)
                acc[mi][ni] = __builtin_amdgcn_mfma_f32_16x16x32_bf16(af[mi], bf[ni], acc[mi][ni], 0, 0, 0);
    }

    // epilogue: D row (m)=b, col (n)=wrow; xp slab [b][3072]
    unsigned short* slab = xp + tC * (BSZ * R3H);
#pragma unroll
    for (int ni = 0; ni < 4; ni++) {
        const int wrow = n0 + nh + ni * 16 + mm;
        const float bs = bias[wrow];
#pragma unroll
        for (int mi = 0; mi < 4; mi++) {
            const int bb = mh + mi * 16 + (q << 2);
#pragma unroll
            for (int r = 0; r < 4; r++)
                slab[(bb + r) * R3H + wrow] = f2b(acc[mi][ni][r] + bs);
        }
    }
}

// ---------------------------------------------------------------------------
// Fence-free grid barrier, one-pass poll: issue all 4 flag-group loads,
// single wave-wide ballot; sleep only on retry.
// ---------------------------------------------------------------------------
__device__ __forceinline__ void gridbar(unsigned* flags, unsigned s) {
    asm volatile("s_waitcnt vmcnt(0)" ::: "memory");
    __syncthreads();
    if (threadIdx.x == 0)
        __hip_atomic_store(&flags[blockIdx.x], s, __ATOMIC_RELAXED, __HIP_MEMORY_SCOPE_AGENT);
    if (threadIdx.x < 64) {
        const unsigned* f = flags + threadIdx.x;
        for (;;) {
            unsigned a0 = __hip_atomic_load(f,       __ATOMIC_RELAXED, __HIP_MEMORY_SCOPE_AGENT);
            unsigned a1 = __hip_atomic_load(f + 64,  __ATOMIC_RELAXED, __HIP_MEMORY_SCOPE_AGENT);
            unsigned a2 = __hip_atomic_load(f + 128, __ATOMIC_RELAXED, __HIP_MEMORY_SCOPE_AGENT);
            unsigned a3 = __hip_atomic_load(f + 192, __ATOMIC_RELAXED, __HIP_MEMORY_SCOPE_AGENT);
            if (__all(a0 >= s && a1 >= s && a2 >= s && a3 >= s)) break;
            __builtin_amdgcn_s_sleep(1);
        }
    }
    __syncthreads();
}

// ---------------------------------------------------------------------------
// Persistent recurrence kernel. 256 wgs x 768 thr (12 waves).
// wg (bt,ot): b in [bt*16,+16), o in [ot*32,+32). Wave (g,kh) holds
// Wh[g][2 o-subtiles][k-quarter] in 64 VGPRs. Per step: stage h slab via
// L3-bypass loads; 8x(ds_read_b128 + 2 MFMA); partials to Cg; elementwise
// with one-step-ahead prefetched xp; h ping-pong via agent atomics.
// ---------------------------------------------------------------------------
__global__ __launch_bounds__(768, 3) void rnn_layer(
    const unsigned short* __restrict__ Whb,   // layer slice [3072][1024] bf16
    const unsigned short* __restrict__ xp,    // [128][128][3072] bf16
    const float* __restrict__ h0,             // [128][1024] fp32
    const float* __restrict__ bh,             // [3][1024] fp32
    unsigned short* __restrict__ hb0,
    unsigned short* __restrict__ hb1,
    unsigned short* __restrict__ seqout,      // layer0 out: bf16 [(b*128+t)*1024+o]
    float* __restrict__ lastlayer,            // layer1 out: fp32
    float* __restrict__ laststep,             // fp32 [b*1024+o]
    unsigned* __restrict__ flags,
    int is_last)
{
    __shared__ unsigned short As[128 * 136];  // 34816 B
    __shared__ float Cg[6528];                // 26112 B: [3g][2os][4kh][16b][17]

    const int bid = blockIdx.x;
    const int bt = bid & 7, ot = bid >> 3;
    const int tid = threadIdx.x;
    const int lane = tid & 63, wv = tid >> 6;
    const int g = wv >> 2, kh = wv & 3;
    const int q = lane >> 4, mm = lane & 15;

    // ---- Wh fragments into registers (once) ----
    short8 wh0[8], wh1[8];
    {
        const unsigned short* p0 = &Whb[((g << 10) + (ot << 5) + mm) * HSZ + (kh << 8) + (q << 3)];
        const unsigned short* p1 = p0 + (HSZ << 4);
#pragma unroll
        for (int s = 0; s < 8; s++) {
            wh0[s] = *(const short8*)(p0 + (s << 5));
            wh1[s] = *(const short8*)(p1 + (s << 5));
        }
    }

    // ---- elementwise ownership: tid<256 owns (b_l, o_l, o_l+1) ----
    float hc0 = 0.f, hc1 = 0.f;
    float bh00 = 0.f, bh01 = 0.f, bh10 = 0.f, bh11 = 0.f, bh20 = 0.f, bh21 = 0.f;
    int b_g = 0, o_g = 0, b_l = 0, o_l = 0;
    unsigned xq0 = 0, xq1 = 0, xq2 = 0;       // prefetched xp (current step)
    if (tid < 256) {
        b_l = tid >> 4; o_l = (tid & 15) << 1;
        b_g = (bt << 4) + b_l;
        o_g = (ot << 5) + o_l;
        float2 v = *(const float2*)&h0[(b_g << 10) + o_g];
        hc0 = v.x; hc1 = v.y;
        bh00 = bh[o_g];        bh01 = bh[o_g + 1];
        bh10 = bh[1024 + o_g]; bh11 = bh[1024 + o_g + 1];
        bh20 = bh[2048 + o_g]; bh21 = bh[2048 + o_g + 1];
        // prefetch xp for t=0 (xp slab [b][3H])
        const unsigned short* x0p = xp + b_g * R3H + o_g;
        xq0 = *(const unsigned*)(x0p);
        xq1 = *(const unsigned*)(x0p + 1024);
        xq2 = *(const unsigned*)(x0p + 2048);
        unsigned pk = (unsigned)f2b(v.x) | ((unsigned)f2b(v.y) << 16);
        __hip_atomic_store((unsigned*)&hb0[(b_g << 10) + o_g], pk,
                           __ATOMIC_RELAXED, __HIP_MEMORY_SCOPE_AGENT);
    }
    gridbar(flags, 1u);

    // staging constants (tid<512)
    const int sb = tid & 15, kcg = (tid >> 4) & 31;

    for (int t = 0; t < TSZ; t++) {
        const unsigned short* hr = (t & 1) ? hb1 : hb0;
        unsigned short* hw = (t & 1) ? hb0 : hb1;

        // ---- stage h slab via L3-bypass loads ----
        if (tid < 512) {
            const unsigned short* src = hr + (((bt << 4) + sb) << 10) + (kcg << 3);
            u32x4 hv[4];
#pragma unroll
            for (int i = 0; i < 4; i++)
                asm volatile("global_load_dwordx4 %0, %1, off sc0 sc1"
                             : "=v"(hv[i]) : "v"(src + (i << 8)));
            asm volatile("s_waitcnt vmcnt(0)" ::: "memory");
#pragma unroll
            for (int i = 0; i < 4; i++)
                *(u32x4*)&As[(kcg + (i << 5)) * 136 + sb * 8] = hv[i];
        }
        __syncthreads();

        // ---- prefetch xp for step t+1 (off the critical chain) ----
        unsigned xn0 = 0, xn1 = 0, xn2 = 0;
        if (tid < 256 && t + 1 < TSZ) {
            const unsigned short* xnp = xp + (t + 1) * (BSZ * R3H) + b_g * R3H + o_g;
            xn0 = *(const unsigned*)(xnp);
            xn1 = *(const unsigned*)(xnp + 1024);
            xn2 = *(const unsigned*)(xnp + 2048);
        }

        // ---- k-loop: pure LDS + MFMA (Wh in registers) ----
        f32x4 acc0 = (f32x4){0.f, 0.f, 0.f, 0.f};
        f32x4 acc1 = (f32x4){0.f, 0.f, 0.f, 0.f};
        {
            const unsigned short* ab = &As[((kh << 5) + q) * 136 + mm * 8];
#pragma unroll
            for (int s = 0; s < 8; s++) {
                short8 a = *(const short8*)(ab + s * 544);
                acc0 = __builtin_amdgcn_mfma_f32_16x16x32_bf16(a, wh0[s], acc0, 0, 0, 0);
                acc1 = __builtin_amdgcn_mfma_f32_16x16x32_bf16(a, wh1[s], acc1, 0, 0, 0);
            }
        }

        // ---- write f32 partials ----
        {
            float* cgw = &Cg[((g << 3) + kh) * 272 + (q << 2) * 17 + mm];
#pragma unroll
            for (int r = 0; r < 4; r++) {
                cgw[r * 17]        = acc0[r];
                cgw[1088 + r * 17] = acc1[r];
            }
        }
        __syncthreads();

        // ---- elementwise: combine partials, gates, h update ----
        if (tid < 256) {
            const int os = o_l >> 4, ol2 = o_l & 15;
            const float* cb = &Cg[os * 1088 + b_l * 17 + ol2];
            float c0a, c0b, c1a, c1b, c2a, c2b;
            {
                const float* p = cb;
                c0a = p[0] + p[272] + p[544] + p[816];
                c0b = p[1] + p[273] + p[545] + p[817];
                p = cb + 2176;
                c1a = p[0] + p[272] + p[544] + p[816];
                c1b = p[1] + p[273] + p[545] + p[817];
                p = cb + 4352;
                c2a = p[0] + p[272] + p[544] + p[816];
                c2b = p[1] + p[273] + p[545] + p[817];
            }
            float res0, res1;
            {
                const float x0 = bf2f((unsigned short)(xq0 & 0xffff));
                const float x1 = bf2f((unsigned short)(xq1 & 0xffff));
                const float x2 = bf2f((unsigned short)(xq2 & 0xffff));
                const float r_ = 1.f / (1.f + __expf(-(x0 + c0a + bh00)));
                const float z_ = 1.f / (1.f + __expf(-(x1 + c1a + bh10)));
                const float nn = x2 + r_ * (c2a + bh20);
                const float th = 1.f - 2.f / (__expf(2.f * nn) + 1.f);
                res0 = (1.f - z_) * th + z_ * hc0;
            }
            {
                const float x0 = bf2f((unsigned short)(xq0 >> 16));
                const float x1 = bf2f((unsigned short)(xq1 >> 16));
                const float x2 = bf2f((unsigned short)(xq2 >> 16));
                const float r_ = 1.f / (1.f + __expf(-(x0 + c0b + bh01)));
                const float z_ = 1.f / (1.f + __expf(-(x1 + c1b + bh11)));
                const float nn = x2 + r_ * (c2b + bh21);
                const float th = 1.f - 2.f / (__expf(2.f * nn) + 1.f);
                res1 = (1.f - z_) * th + z_ * hc1;
            }
            hc0 = res0; hc1 = res1;
            const unsigned pk = (unsigned)f2b(res0) | ((unsigned)f2b(res1) << 16);
            __hip_atomic_store((unsigned*)&hw[(b_g << 10) + o_g], pk,
                               __ATOMIC_RELAXED, __HIP_MEMORY_SCOPE_AGENT);
            if (!is_last) {
                *(unsigned*)&seqout[(b_g * TSZ + t) * HSZ + o_g] = pk;
            } else {
                float2 fv; fv.x = res0; fv.y = res1;
                *(float2*)&lastlayer[((b_g * TSZ + t) << 10) + o_g] = fv;
            }
            if (t == TSZ - 1) {
                float2 fv; fv.x = res0; fv.y = res1;
                *(float2*)&laststep[(b_g << 10) + o_g] = fv;
            }
        }
        xq0 = xn0; xq1 = xn1; xq2 = xn2;
        gridbar(flags, (unsigned)(t + 2));
    }
}

// ---------------------------------------------------------------------------
// Host orchestration. ws layout (bytes):
//   Wxb 0..12582912 | Whb ..25165824 | inb ..58720256 | h1seq ..92274688 |
//   xp ..192937984 | hb0 ..193200128 | hb1 ..193462272 | flags(2KB)
// ---------------------------------------------------------------------------
extern "C" void kernel_launch(void* const* d_in, const int* in_sizes, int n_in,
                              void* d_out, int out_size, void* d_ws, size_t ws_size,
                              hipStream_t stream)
{
    const float* input = (const float*)d_in[0];
    const float* prevh = (const float*)d_in[1];
    const float* Wx    = (const float*)d_in[2];
    const float* Wh    = (const float*)d_in[3];
    const float* bx    = (const float*)d_in[4];
    const float* bh    = (const float*)d_in[5];
    float* out = (float*)d_out;

    char* ws = (char*)d_ws;
    unsigned short* Wxb = (unsigned short*)(ws);
    unsigned short* Whb = (unsigned short*)(ws + 12582912);
    unsigned short* inb = (unsigned short*)(ws + 25165824);
    unsigned short* h1s = (unsigned short*)(ws + 58720256);
    unsigned short* xp  = (unsigned short*)(ws + 92274688);
    unsigned short* hb0 = (unsigned short*)(ws + 192937984);
    unsigned short* hb1 = (unsigned short*)(ws + 193200128);
    unsigned*       flg = (unsigned*)(ws + 193462272);

    (void)hipMemsetAsync(flg, 0, 2048, stream);

    cvt_bf16<<<2048, 256, 0, stream>>>(input, inb, BTH / 4);
    cvt_bf16<<<1024, 256, 0, stream>>>(Wx, Wxb, 6291456 / 4);
    cvt_bf16<<<1024, 256, 0, stream>>>(Wh, Whb, 6291456 / 4);

    // ---- layer 0 ----
    gemm_xp<<<dim3(128, 24), 256, 0, stream>>>(inb, Wxb, bx, xp);
    {
        const unsigned short* a0 = Whb;
        const unsigned short* a1 = xp;
        const float* a2 = prevh;
        const float* a3 = bh;
        unsigned short* a4 = hb0;
        unsigned short* a5 = hb1;
        unsigned short* a6 = h1s;
        float* a7 = out;
        float* a8 = out + BTH;            // last_step layer 0
        unsigned* a9 = flg;
        int a10 = 0;
        void* args[] = {&a0, &a1, &a2, &a3, &a4, &a5, &a6, &a7, &a8, &a9, &a10};
        (void)hipLaunchCooperativeKernel((const void*)rnn_layer, dim3(NWG), dim3(768),
                                         args, 0, stream);
    }
    // ---- layer 1 ----
    gemm_xp<<<dim3(128, 24), 256, 0, stream>>>(h1s, Wxb + 3145728, bx + R3H, xp);
    {
        const unsigned short* a0 = Whb + 3145728;
        const unsigned short* a1 = xp;
        const float* a2 = prevh + BH;
        const float* a3 = bh + R3H;
        unsigned short* a4 = hb0;
        unsigned short* a5 = hb1;
        unsigned short* a6 = h1s;
        float* a7 = out;                  // last_layer_hiddens
        float* a8 = out + BTH + BH;       // last_step layer 1
        unsigned* a9 = flg + 256;
        int a10 = 1;
        void* args[] = {&a0, &a1, &a2, &a3, &a4, &a5, &a6, &a7, &a8, &a9, &a10};
        (void)hipLaunchCooperativeKernel((const void*)rnn_layer, dim3(NWG), dim3(768),
                                         args, 0, stream);
    }
}